// Round 5
// baseline (223.427 us; speedup 1.0000x reference)
//
#include <hip/hip_runtime.h>

// ConvLSTM cell on MI355X (gfx950) — round 8.
// Implicit GEMM M=256 (4 gates x 64 oc), K=864 (96ch x 9 taps), N=131072.
// bf16 MFMA 32x32x16.
// Round-8 change vs round-7 (79.5us, MfmaUtil 32%): the LDS READ pipe was the
// floor (6912 ds_read_b128/CU x 12cyc = 35us > 23us MFMA floor). New wave
// tile 2x4: M=64 x N=128 (2 output rows) per wave -> 8 MFMA from 6 ds_reads
// (+33% FLOP/read, A-read redundancy eliminated). Block = 4 waves (256 thr),
// same 2-row output, same B-LDS (4 P-rows), same 75264 B LDS -> 2 blocks/CU.
// acc = 8 x f32x16 = 128 AGPR -> 2 waves/SIMD (launch_bounds(256,2), budget
// ~170 <= 256 regs). Counted-vmcnt triple-buffered A staging kept (2 gl_lds
// per thread per phase, waits vmcnt(2)). setprio(1) around MFMA cluster.

#define B_   32
#define CIN  32
#define HC_  64
#define HH   64
#define WW   64

#define A_ELEMS (9 * 6 * 8 * 64 * 8)     // 221184 bf16 = 256 x 864 packed A
#define P_ROW   (12 * 66 * 8)            // shorts per P' row = 6336
#define AKK     4096                     // shorts per 1-kk A chunk (8 KB)
#define BLDS    25344                    // shorts of B in LDS (4 rows)

typedef __attribute__((ext_vector_type(8)))  short  short8;
typedef __attribute__((ext_vector_type(16))) float  floatx16;

struct PackArgs {
    const float* wx[4]; const float* wh[4];
    const float* bx[4]; const float* bh[4];
};

__device__ __forceinline__ short f2bf(float f) {
    unsigned u = __float_as_uint(f);
    u += 0x7FFFu + ((u >> 16) & 1u);     // round-to-nearest-even
    return (short)(u >> 16);
}

__device__ __forceinline__ void gl_lds16(const short* g, short* l) {
    __builtin_amdgcn_global_load_lds(
        (const __attribute__((address_space(1))) unsigned int*)g,
        (__attribute__((address_space(3))) unsigned int*)l, 16, 0, 0);
}

// ---- pack A: [tap 9][kk 6][s 8][lane 64][j 8] ------------------------------
// s = og*2+fi ; m32 = lane&31 ; gate = 2*fi + (m32>>4) ; oc = og*16 + (m32&15)
// c = kk*16 + (lane>>5)*8 + j  (A-operand: m = lane&31, k = (lane>>5)*8+j)
__global__ __launch_bounds__(256) void pack_weights(PackArgs pa, short* a_pk, float* bias) {
    int idx = blockIdx.x * 256 + threadIdx.x;
    if (idx < A_ELEMS) {
        int j    = idx & 7;
        int lane = (idx >> 3) & 63;
        int rest = idx >> 9;             // (tap*6 + kk)*8 + s
        int s    = rest & 7;
        int rest2 = rest >> 3;
        int kk   = rest2 % 6;
        int tap  = rest2 / 6;
        int og = s >> 1, fi = s & 1;
        int m32 = lane & 31;
        int gate = 2 * fi + (m32 >> 4);
        int oc   = og * 16 + (m32 & 15);
        int c    = kk * 16 + (lane >> 5) * 8 + j;
        int ky = tap / 3, kx = tap - 3 * ky;
        float v = (c < CIN)
            ? pa.wx[gate][((oc * CIN + c) * 3 + ky) * 3 + kx]
            : pa.wh[gate][((oc * HC_ + (c - CIN)) * 3 + ky) * 3 + kx];
        a_pk[idx] = f2bf(v);
    }
    if (idx < 256) {
        int gate = idx >> 6, oc = idx & 63;
        bias[idx] = pa.bx[gate][oc] + pa.bh[gate][oc];
    }
}

// ---- pack x||h -> P'[b][yy][pc 12][xx 66][8ch] bf16, zero borders ----------
__global__ __launch_bounds__(256) void pack_input(const float* __restrict__ x,
                                                  const float* __restrict__ h,
                                                  short* __restrict__ P) {
    const int yy = blockIdx.x, b = blockIdx.y;
    int4* prow4 = (int4*)(P + ((size_t)b * 66 + yy) * P_ROW);  // 792 chunks

    if (yy == 0 || yy == 65) {
        int4 z = {0, 0, 0, 0};
        for (int g = threadIdx.x; g < 792; g += 256) prow4[g] = z;
        return;
    }

    __shared__ short t[64 * 98];                     // [x][c], pad 96->98
    const int y = yy - 1;
    const int col = threadIdx.x & 63, cg = threadIdx.x >> 6;
    for (int c = cg; c < 96; c += 4) {
        float v = (c < CIN) ? x[((b * CIN + c) * HH + y) * WW + col]
                            : h[((b * HC_ + (c - CIN)) * HH + y) * WW + col];
        t[col * 98 + c] = f2bf(v);
    }
    __syncthreads();

    for (int g = threadIdx.x; g < 792; g += 256) {   // pc = g/66, xx = g%66
        int pc = g / 66, xx = g - 66 * pc;
        int4 val = {0, 0, 0, 0};
        if (xx >= 1 && xx <= 64) {
            const short* sp = &t[(xx - 1) * 98 + pc * 8];
            val.x = *(const int*)(sp + 0); val.y = *(const int*)(sp + 2);
            val.z = *(const int*)(sp + 4); val.w = *(const int*)(sp + 6);
        }
        prow4[g] = val;
    }
}

// ---- main: grid 1024 = (b 32)x(rowpair 32), 256 thr = 4 waves --------------
// wave = og(0..3): M-tile = 4 gates x 16 oc, N-tile = 2 rows x 64 cols.
// acc[fi][rr][ns] = 8 x f32x16 = 128 AGPR. 2 blocks/CU (LDS 75264 x2).
// LDS: [B 4 rows x 6336][A buf0..2 x 4096] shorts. 54 phases, A triple-buf,
// depth-2 prefetch, counted vmcnt(2) + s_barrier per phase (no drain).
__global__ __launch_bounds__(256, 2) void convlstm_main(
    const short* __restrict__ P, const short* __restrict__ a_pk,
    const float* __restrict__ bias, const float* __restrict__ cell,
    float* __restrict__ out)
{
    __shared__ __align__(16) short lds[BLDS + 3 * AKK];   // 75264 B

    const int tid = threadIdx.x;
    const int b  = blockIdx.x >> 5;
    const int y0 = (blockIdx.x & 31) * 2;

    const int wv = tid >> 6, lane = tid & 63;        // wv = og
    const int ln31 = lane & 31, hg = lane >> 5;
    const int og = wv;

    floatx16 acc[2][2][2];                           // [fi][rr][ns]
    #pragma unroll
    for (int fi = 0; fi < 2; ++fi)
        #pragma unroll
        for (int rr = 0; rr < 2; ++rr)
            #pragma unroll
            for (int ns = 0; ns < 2; ++ns)
                #pragma unroll
                for (int q = 0; q < 16; ++q) acc[fi][rr][ns][q] = 0.f;

    short* Asl = lds + BLDS;                         // 3 x 4096 shorts
    const int a_rd   = og * 1024 + lane * 8;         // + (c%3)*4096 + fi*512
    const int b_lane = hg * 528 + ln31 * 8;          // + (rr+ky)*6336+2kk*528+(ns*32+kx)*8

    // ---- prologue: B rows y0..y0+3 (3168 chunks / 256 thr) + A chunks 0,1
    {
        const short* Bsrc = P + ((size_t)(b * 66) + y0) * P_ROW;
        #pragma unroll
        for (int i = 0; i < 13; ++i) {
            int id = i * 256 + tid;
            if (id < 3168)
                gl_lds16(Bsrc + id * 8, lds + (i * 256 + wv * 64) * 8);
        }
        #pragma unroll
        for (int ck = 0; ck < 2; ++ck)
            #pragma unroll
            for (int i = 0; i < 2; ++i)
                gl_lds16(a_pk + ck * AKK + (i * 256 + tid) * 8,
                         Asl + ck * AKK + (i * 256 + wv * 64) * 8);
    }
    asm volatile("s_waitcnt vmcnt(2)" ::: "memory");  // B + chunk0 landed
    __builtin_amdgcn_s_barrier();
    __builtin_amdgcn_sched_barrier(0);

    #pragma unroll
    for (int c = 0; c < 54; ++c) {
        const int tap = c / 6, kk = c % 6;
        const int ky = tap / 3, kx = tap % 3;

        // issue stage(c+2) into buf[(c+2)%3] (2 gl_lds per thread)
        if (c < 52) {
            const short* src = a_pk + (c + 2) * AKK;
            short* dst = Asl + ((c + 2) % 3) * AKK;
            gl_lds16(src + tid * 8,         dst + (wv * 64) * 8);
            gl_lds16(src + (256 + tid) * 8, dst + (256 + wv * 64) * 8);
        }

        const short* Ab = Asl + (c % 3) * AKK + a_rd;
        const short* Bb = lds + b_lane + ky * 6336 + 2 * kk * 528 + kx * 8;

        short8 a0  = *(const short8*)&Ab[0];
        short8 a1  = *(const short8*)&Ab[512];
        short8 b00 = *(const short8*)&Bb[0];
        short8 b01 = *(const short8*)&Bb[256];
        short8 b10 = *(const short8*)&Bb[6336];
        short8 b11 = *(const short8*)&Bb[6336 + 256];

        __builtin_amdgcn_s_setprio(1);
        acc[0][0][0] = __builtin_amdgcn_mfma_f32_32x32x16_bf16(a0, b00, acc[0][0][0], 0, 0, 0);
        acc[0][0][1] = __builtin_amdgcn_mfma_f32_32x32x16_bf16(a0, b01, acc[0][0][1], 0, 0, 0);
        acc[0][1][0] = __builtin_amdgcn_mfma_f32_32x32x16_bf16(a0, b10, acc[0][1][0], 0, 0, 0);
        acc[0][1][1] = __builtin_amdgcn_mfma_f32_32x32x16_bf16(a0, b11, acc[0][1][1], 0, 0, 0);
        acc[1][0][0] = __builtin_amdgcn_mfma_f32_32x32x16_bf16(a1, b00, acc[1][0][0], 0, 0, 0);
        acc[1][0][1] = __builtin_amdgcn_mfma_f32_32x32x16_bf16(a1, b01, acc[1][0][1], 0, 0, 0);
        acc[1][1][0] = __builtin_amdgcn_mfma_f32_32x32x16_bf16(a1, b10, acc[1][1][0], 0, 0, 0);
        acc[1][1][1] = __builtin_amdgcn_mfma_f32_32x32x16_bf16(a1, b11, acc[1][1][1], 0, 0, 0);
        __builtin_amdgcn_s_setprio(0);

        // close phase: counted wait (stage(c+1) landed, stage(c+2) in flight)
        if (c < 52)       asm volatile("s_waitcnt vmcnt(2)" ::: "memory");
        else if (c == 52) asm volatile("s_waitcnt vmcnt(0)" ::: "memory");
        if (c < 53) {
            __builtin_amdgcn_s_barrier();
            __builtin_amdgcn_sched_barrier(0);
        }
    }

    // ---- lane-local LSTM epilogue --------------------------------------
    // C/D 32x32 map: col = ln31, row r32 = (r&3) + 4*hg + 8*(r>>2).
    // acc[fi][..] rows: r32<16 -> gate 2fi, oc16=r32 ; r32>=16 -> gate 2fi+1.
    const size_t plane = (size_t)B_ * HC_ * HH * WW;
    #pragma unroll
    for (int q = 0; q < 4; ++q)
    #pragma unroll
    for (int b8 = 0; b8 < 2; ++b8) {
        const int oc16 = q + 4 * hg + 8 * b8;
        const int oc = og * 16 + oc16;
        const float Bi = bias[oc],       Bf = bias[64 + oc];
        const float Bo = bias[128 + oc], Bg = bias[192 + oc];
        const int r_lo = q + 4 * b8, r_hi = q + 4 * (2 + b8);
        #pragma unroll
        for (int rr = 0; rr < 2; ++rr)
        #pragma unroll
        for (int ns = 0; ns < 2; ++ns) {
            float zi = acc[0][rr][ns][r_lo] + Bi;
            float zf = acc[0][rr][ns][r_hi] + Bf;
            float zo = acc[1][rr][ns][r_lo] + Bo;
            float zg = acc[1][rr][ns][r_hi] + Bg;
            float ig = 1.f / (1.f + __expf(-zi));
            float fg = 1.f / (1.f + __expf(-zf));
            float sg = 1.f / (1.f + __expf(-zo));
            float e2 = __expf(2.f * zg);
            float gg = 1.f - 2.f / (e2 + 1.f);               // tanh(zg)
            const int x = ns * 32 + ln31;
            const int y = y0 + rr;
            size_t off = ((size_t)(b * HC_ + oc) * HH + y) * WW + x;
            float cn = fg * cell[off] + ig * gg;
            float ec = __expf(2.f * cn);
            out[off] = sg * (1.f - 2.f / (ec + 1.f));        // h_new
            out[plane + off] = cn;                           // c_new
        }
    }
}

extern "C" void kernel_launch(void* const* d_in, const int* in_sizes, int n_in,
                              void* d_out, int out_size, void* d_ws, size_t ws_size,
                              hipStream_t stream) {
    PackArgs pa;
    pa.wx[0] = (const float*)d_in[3];  pa.bx[0] = (const float*)d_in[4];
    pa.wx[1] = (const float*)d_in[5];  pa.bx[1] = (const float*)d_in[6];
    pa.wx[2] = (const float*)d_in[7];  pa.bx[2] = (const float*)d_in[8];
    pa.wx[3] = (const float*)d_in[9];  pa.bx[3] = (const float*)d_in[10];
    pa.wh[0] = (const float*)d_in[11]; pa.bh[0] = (const float*)d_in[12];
    pa.wh[1] = (const float*)d_in[13]; pa.bh[1] = (const float*)d_in[14];
    pa.wh[2] = (const float*)d_in[15]; pa.bh[2] = (const float*)d_in[16];
    pa.wh[3] = (const float*)d_in[17]; pa.bh[3] = (const float*)d_in[18];

    short* a_pk = (short*)d_ws;                                    // 442368 B
    float* bias = (float*)((char*)d_ws + A_ELEMS * sizeof(short)); // 1024 B
    short* P    = (short*)((char*)d_ws + 443392);                  // 26.76 MB

    pack_weights<<<dim3(A_ELEMS / 256), dim3(256), 0, stream>>>(pa, a_pk, bias);
    pack_input <<<dim3(66, B_), dim3(256), 0, stream>>>(
        (const float*)d_in[0], (const float*)d_in[1], P);
    convlstm_main<<<dim3(B_ * 32), dim3(256), 0, stream>>>(
        P, a_pk, bias, (const float*)d_in[2], (float*)d_out);
}